// Round 16
// baseline (64.979 us; speedup 1.0000x reference)
//
#include <hip/hip_runtime.h>
#include <stdint.h>

// ---- problem constants ----
#define T_TOK 2048
#define H_DIM 1024
#define ID    512    // I
#define E_NUM 8
#define NPAIR 4096   // T_TOK * top_k(2)
#define BM    128
#define MAXTILES 40  // sum ceil(cnt_e/128) <= 32 + 7

typedef _Float16 half_t;
typedef _Float16 f16x8 __attribute__((ext_vector_type(8)));
typedef _Float16 f16x4 __attribute__((ext_vector_type(4)));
typedef float    f32x4 __attribute__((ext_vector_type(4)));

// ---- workspace layout (bytes) ----
#define XB_OFF      ((size_t)0)               // f16 [2048][1024]    4 MiB
#define WGU_OFF     ((size_t)(4u << 20))      // f16 [8][1024][1024] (f-major, k=h contig) 16 MiB
#define WDN_OFF     ((size_t)(20u << 20))     // f16 [8][1024][512]  (h-major, k=i contig)  8 MiB
#define INTER_OFF   ((size_t)(28u << 20))     // f16 [4096][512]     4 MiB
#define META_OFF    ((size_t)(32u << 20))     // ints (see below)
#define PAIRW_OFF   ((size_t)((32u << 20) + 65536))
#define CONTRIB_OFF ((size_t)(36u << 20))     // f32 [4096][1024]   16 MiB
// meta: [0]=ntiles, [8..48) tile_e, [88..128) tile_row0, [168..208) tile_end,
//       [256..256+4096) pair_token, [256+4096..256+8192) slot_of

__device__ __forceinline__ void gload_lds16(const void* g, void* l) {
    __builtin_amdgcn_global_load_lds(
        (const __attribute__((address_space(1))) unsigned int*)g,
        (__attribute__((address_space(3))) unsigned int*)l,
        16, 0, 0);
}

// 64x64 transpose-convert tile: reads in[r0+r][c0+c] (row stride 1024, f32),
// writes out[(c0+c)*out_stride + r0 + r] (f16). smem >= 64*65*4 bytes.
template <int NT>
__device__ __forceinline__ void cvt_tile64(const float* __restrict__ in,
                                           half_t* __restrict__ out,
                                           int r0, int c0, int out_stride,
                                           char* smem) {
    float (*tile)[65] = (float(*)[65])smem;
    int tid = threadIdx.x;
#pragma unroll
    for (int it = 0; it < 1024 / NT; it++) {
        int idx = tid + it * NT;
        int r = idx >> 4, c4 = (idx & 15) * 4;
        float4 v = *(const float4*)(in + (size_t)(r0 + r) * 1024 + c0 + c4);
        tile[r][c4] = v.x; tile[r][c4 + 1] = v.y; tile[r][c4 + 2] = v.z; tile[r][c4 + 3] = v.w;
    }
    __syncthreads();
#pragma unroll
    for (int it = 0; it < 1024 / NT; it++) {
        int idx = tid + it * NT;
        int oc = idx >> 4, r4 = (idx & 15) * 4;
        f16x4 o;
        o[0] = (half_t)tile[r4][oc];
        o[1] = (half_t)tile[r4 + 1][oc];
        o[2] = (half_t)tile[r4 + 2][oc];
        o[3] = (half_t)tile[r4 + 3][oc];
        *(f16x4*)(out + (size_t)(c0 + oc) * out_stride + r0 + r4) = o;
    }
}

// ---- fused prep: cvt x->f16 | route | cvt gate_up weights ----
// grid: [0,1024) cvt_x, [1024] route, [1025,3073) cvt_wgu
__global__ __launch_bounds__(256) void k_prep(const float* __restrict__ x,
                                              const int* __restrict__ ridx,
                                              const float* __restrict__ rw,
                                              const float* __restrict__ wgu,
                                              half_t* __restrict__ xb,
                                              half_t* __restrict__ wguT,
                                              int* __restrict__ meta,
                                              float* __restrict__ pair_w) {
    __shared__ char smem[16704];
    int b = blockIdx.x, tid = threadIdx.x;
    if (b < 1024) {
        int g = b * 256 + tid;
        size_t b0 = (size_t)g * 8;
        float4 v0 = *(const float4*)(x + b0);
        float4 v1 = *(const float4*)(x + b0 + 4);
        f16x8 o;
        o[0] = (half_t)v0.x; o[1] = (half_t)v0.y; o[2] = (half_t)v0.z; o[3] = (half_t)v0.w;
        o[4] = (half_t)v1.x; o[5] = (half_t)v1.y; o[6] = (half_t)v1.z; o[7] = (half_t)v1.w;
        *(f16x8*)(xb + b0) = o;
    } else if (b == 1024) {
        __shared__ int cnt[E_NUM], cur[E_NUM], base[E_NUM];
        if (tid < E_NUM) { cnt[tid] = 0; cur[tid] = 0; }
        __syncthreads();
        for (int i = tid; i < NPAIR; i += 256) atomicAdd(&cnt[ridx[i]], 1);
        __syncthreads();
        if (tid == 0) {
            int acc = 0, nt = 0;
            for (int e = 0; e < E_NUM; e++) {
                base[e] = acc;
                for (int r = 0; r < cnt[e]; r += BM) {
                    meta[8 + nt] = e; meta[88 + nt] = acc + r; meta[168 + nt] = acc + cnt[e]; nt++;
                }
                acc += cnt[e];
            }
            meta[0] = nt;
        }
        __syncthreads();
        for (int i = tid; i < NPAIR; i += 256) {
            int e = ridx[i];
            int pos = atomicAdd(&cur[e], 1);
            int slot = base[e] + pos;
            meta[256 + slot] = i >> 1;            // pair_token[slot] = t
            meta[256 + NPAIR + i] = slot;         // slot_of[pair i]
            pair_w[slot] = rw[i];
        }
    } else {
        int t = b - 1025;                 // [0, 2048): gate_up expert tiles
        int e = t >> 8, rem = t & 255;
        int h0 = (rem >> 4) * 64, f0 = (rem & 15) * 64;
        cvt_tile64<256>(wgu + (size_t)e * 1024 * 1024, wguT + (size_t)e * 1024 * 1024,
                        h0, f0, 1024, smem);
    }
}

// 4-wave GEMM (2x2 waves of 64x64 = acc[4][4]), block tile 128 rows x 128 B-rows, BK=64.
// Proven __syncthreads dbuf pipeline (R8/R15): stage(kt+1) before compute(kt), one
// barrier/K-step; 32 MFMA + 16 ds_read per wave per barrier (was 16+12 at 64-tile).
// LDS 2 x 32 KiB = 64 KiB -> 2 blocks/CU. 8-slot XOR swizzle (R15: 0 bank conflicts).
// MODE 0: A = xb gathered (K=1024), B = wguT remapped (fn{0,1}=gate, fn{2,3}=up);
//         epilogue = in-register SwiGLU -> inter f16. aux: [320,1344) cvt down-proj.
// MODE 1: A = inter (K=512), B = wdnT; epilogue = plain stores acc*pair_w -> contrib.
template <int MODE>
__global__ __launch_bounds__(256) void k_gemm(const int* __restrict__ meta,
                                              const half_t* __restrict__ amat,
                                              const half_t* __restrict__ wT,
                                              const float* __restrict__ pair_w,
                                              void* __restrict__ outp,
                                              const float* __restrict__ aux_in,
                                              half_t* __restrict__ aux_out) {
    constexpr int KSZ = MODE ? ID : H_DIM;
    constexpr int NKT = KSZ / 64;
    __shared__ __align__(16) char smem[65536];   // 2 bufs x (A 16K | B 16K); cvt aliases

    int d = blockIdx.x;
    if (MODE == 0 && d >= 320) {
        int d2 = d - 320;          // cvt down-proj: in [e][512 i][1024 h] -> out [e][h][i]
        int e = d2 >> 7, rem = d2 & 127;
        int h0 = (rem >> 3) * 64, i0 = (rem & 7) * 64;
        cvt_tile64<256>(aux_in + (size_t)e * ID * 1024, aux_out + (size_t)e * 1024 * ID,
                        i0, h0, ID, smem);
        return;
    }

    int l = (d & 7) * MAXTILES + (d >> 3);    // XCD c owns l in [c*40, c*40+40)
    int bx = l >> 3, by = l & 7;              // 5 consecutive row-tiles/XCD
    int nt = meta[0];
    if (bx >= nt) return;
    int e = meta[8 + bx], row0 = meta[88 + bx], rend = meta[168 + bx];
    const int* pair_token = meta + 256;

    int tid = threadIdx.x, lane = tid & 63, wid = tid >> 6;   // 4 waves
    int wm = wid >> 1, wn = wid & 1;                          // 2x2 of 64x64

    // ---- staging: A tile [128 rows][64 halves] = 16 KiB = 16 chunks; B same.
    // chunk = 1 KiB = 8 rows x 128 B; lane: row = gch*8 + (lane>>3), slot pc = lane&7
    // holds global k-chunk pc ^ (r&7) (inverse-swz source, linear LDS dest).
    const half_t* asrc[4]; int aoff[4];
#pragma unroll
    for (int i = 0; i < 4; i++) {
        int gch = wid * 4 + i;
        int r = gch * 8 + (lane >> 3), pc = lane & 7, lc = pc ^ (r & 7);
        int pr = row0 + r; if (pr > NPAIR - 1) pr = NPAIR - 1;
        const half_t* rowp = (MODE == 0) ? amat + (size_t)pair_token[pr] * KSZ
                                         : amat + (size_t)pr * KSZ;
        asrc[i] = rowp + lc * 8;
        aoff[i] = gch * 1024 + lane * 16;
    }
    const half_t* wbase = wT + (size_t)e * 1024 * KSZ;
    const half_t* bsrc[4]; int boff[4];
#pragma unroll
    for (int i = 0; i < 4; i++) {
        int gch = wid * 4 + i;
        int r = gch * 8 + (lane >> 3), pc = lane & 7, lc = pc ^ (r & 7);
        int physcol;
        if (MODE == 0) {
            int wn_r = r >> 6, f_r = (r >> 4) & 3, ll = r & 15;
            physcol = by * 64 + wn_r * 32 + (f_r & 1) * 16 + ll + ((f_r & 2) ? 512 : 0);
        } else {
            physcol = by * 128 + r;
        }
        bsrc[i] = wbase + (size_t)physcol * KSZ + lc * 8;
        boff[i] = 16384 + gch * 1024 + lane * 16;
    }

#define STAGE(buf, kt)                                                             \
    {                                                                              \
        _Pragma("unroll")                                                          \
        for (int i = 0; i < 4; i++)                                                \
            gload_lds16(asrc[i] + (kt) * 64, smem + (buf) * 32768 + aoff[i]);      \
        _Pragma("unroll")                                                          \
        for (int i = 0; i < 4; i++)                                                \
            gload_lds16(bsrc[i] + (kt) * 64, smem + (buf) * 32768 + boff[i]);      \
    }

    f32x4 acc[4][4] = {};

    STAGE(0, 0);
    __syncthreads();   // buf0 ready

    for (int kt = 0; kt < NKT; kt++) {
        int cur = kt & 1;
        if (kt + 1 < NKT) STAGE(cur ^ 1, kt + 1);   // issue next tile early
        const char* Ab = smem + cur * 32768;
        const char* Bb = Ab + 16384;
#pragma unroll
        for (int ks = 0; ks < 2; ks++) {
            f16x8 af[4], bf[4];
#pragma unroll
            for (int f = 0; f < 4; f++) {
                int ar = wm * 64 + f * 16 + (lane & 15);
                int apc = (ks * 4 + (lane >> 4)) ^ (ar & 7);
                af[f] = *(const f16x8*)(Ab + ar * 128 + apc * 16);
                int br = wn * 64 + f * 16 + (lane & 15);
                int bpc = (ks * 4 + (lane >> 4)) ^ (br & 7);
                bf[f] = *(const f16x8*)(Bb + br * 128 + bpc * 16);
            }
#pragma unroll
            for (int fm = 0; fm < 4; fm++)
#pragma unroll
                for (int fn = 0; fn < 4; fn++)
                    acc[fm][fn] = __builtin_amdgcn_mfma_f32_16x16x32_f16(af[fm], bf[fn], acc[fm][fn], 0, 0, 0);
        }
        __syncthreads();   // drains vmcnt: next buf ready; all reads of cur done
    }

    // C/D layout: col = lane&15, row = (lane>>4)*4 + j
    if (MODE == 0) {
        half_t* inter = (half_t*)outp;
#pragma unroll
        for (int fm = 0; fm < 4; fm++) {
            int rbase = wm * 64 + fm * 16 + (lane >> 4) * 4;
#pragma unroll
            for (int j = 0; j < 4; j++) {
                int packed = row0 + rbase + j;
                if (packed < rend) {
                    half_t* rowp = inter + (size_t)packed * ID;
#pragma unroll
                    for (int fn = 0; fn < 2; fn++) {
                        int col = by * 64 + wn * 32 + fn * 16 + (lane & 15);
                        float g = acc[fm][fn][j], u = acc[fm][fn + 2][j];
                        rowp[col] = (half_t)(g / (1.0f + __expf(-g)) * u);
                    }
                }
            }
        }
    } else {
        float* contrib = (float*)outp;
#pragma unroll
        for (int fm = 0; fm < 4; fm++) {
            int rbase = wm * 64 + fm * 16 + (lane >> 4) * 4;
#pragma unroll
            for (int j = 0; j < 4; j++) {
                int packed = row0 + rbase + j;
                if (packed < rend) {
                    float pw = pair_w[packed];
#pragma unroll
                    for (int fn = 0; fn < 4; fn++) {
                        int col = by * 128 + wn * 64 + fn * 16 + (lane & 15);
                        contrib[(size_t)packed * H_DIM + col] = acc[fm][fn][j] * pw;
                    }
                }
            }
        }
    }
#undef STAGE
}

// out[t] = contrib[slot_of[2t]] + contrib[slot_of[2t+1]]  (deterministic, no atomics)
__global__ __launch_bounds__(256) void k_gather(const float* __restrict__ contrib,
                                                const int* __restrict__ meta,
                                                float* __restrict__ out) {
    int t = blockIdx.x, c4 = threadIdx.x * 4;
    const int* slot_of = meta + 256 + NPAIR;
    int s0 = slot_of[2 * t], s1 = slot_of[2 * t + 1];
    float4 a = *(const float4*)(contrib + (size_t)s0 * H_DIM + c4);
    float4 b = *(const float4*)(contrib + (size_t)s1 * H_DIM + c4);
    float4 o;
    o.x = a.x + b.x; o.y = a.y + b.y; o.z = a.z + b.z; o.w = a.w + b.w;
    *(float4*)(out + (size_t)t * H_DIM + c4) = o;
}

extern "C" void kernel_launch(void* const* d_in, const int* in_sizes, int n_in,
                              void* d_out, int out_size, void* d_ws, size_t ws_size,
                              hipStream_t stream) {
    const float* x    = (const float*)d_in[0];
    const int*   ridx = (const int*)d_in[1];
    const float* rw   = (const float*)d_in[2];
    const float* wgu  = (const float*)d_in[3];
    const float* wdn  = (const float*)d_in[4];
    float* out = (float*)d_out;

    char* ws = (char*)d_ws;
    half_t* xb      = (half_t*)(ws + XB_OFF);
    half_t* wguT    = (half_t*)(ws + WGU_OFF);
    half_t* wdnT    = (half_t*)(ws + WDN_OFF);
    half_t* inter   = (half_t*)(ws + INTER_OFF);
    int*    meta    = (int*)(ws + META_OFF);
    float*  pair_w  = (float*)(ws + PAIRW_OFF);
    float*  contrib = (float*)(ws + CONTRIB_OFF);

    // L1: cvt_x (1024) | route (1) | cvt gate_up (2048)
    k_prep<<<3073, 256, 0, stream>>>(x, ridx, rw, wgu, xb, wguT, meta, pair_w);
    // L2: GEMM1 (320) | cvt down (1024)
    k_gemm<0><<<1344, 256, 0, stream>>>(meta, xb, wguT, pair_w, inter, wdn, wdnT);
    // L3: GEMM2 (320) -> contrib, plain stores
    k_gemm<1><<<320, 256, 0, stream>>>(meta, inter, wdnT, pair_w, contrib, nullptr, nullptr);
    // L4: gather (2048)
    k_gather<<<T_TOK, 256, 0, stream>>>(contrib, meta, out);
}

// Round 17
// 59.592 us; speedup vs baseline: 1.0904x; 1.0904x over previous
//
#include <hip/hip_runtime.h>
#include <stdint.h>

// ---- problem constants ----
#define T_TOK 2048
#define H_DIM 1024
#define ID    512    // I
#define E_NUM 8
#define NPAIR 4096   // T_TOK * top_k(2)
#define BM    64
#define MAXTILES 72  // sum ceil(cnt_e/64) <= 64 + 7

typedef _Float16 half_t;
typedef _Float16 f16x8 __attribute__((ext_vector_type(8)));
typedef _Float16 f16x4 __attribute__((ext_vector_type(4)));
typedef float    f32x4 __attribute__((ext_vector_type(4)));

// ---- workspace layout (bytes) ----
#define XB_OFF      ((size_t)0)               // f16 [2048][1024]    4 MiB
#define WGU_OFF     ((size_t)(4u << 20))      // f16 [8][1024][1024] (f-major, k=h contig) 16 MiB
#define WDN_OFF     ((size_t)(20u << 20))     // f16 [8][1024][512]  (h-major, k=i contig)  8 MiB
#define INTER_OFF   ((size_t)(28u << 20))     // f16 [4096][512]     4 MiB
#define META_OFF    ((size_t)(32u << 20))     // ints (see below)
#define PAIRW_OFF   ((size_t)((32u << 20) + 65536))
#define CONTRIB_OFF ((size_t)(36u << 20))     // f16 [4096][1024]    8 MiB
// meta: [0]=ntiles, [8..80) tile_e, [88..160) tile_row0, [168..240) tile_end,
//       [256..256+4096) pair_token, [256+4096..256+8192) slot_of

__device__ __forceinline__ void gload_lds16(const void* g, void* l) {
    __builtin_amdgcn_global_load_lds(
        (const __attribute__((address_space(1))) unsigned int*)g,
        (__attribute__((address_space(3))) unsigned int*)l,
        16, 0, 0);
}

// 64x64 transpose-convert tile: reads in[r0+r][c0+c] (row stride 1024, f32),
// writes out[(c0+c)*out_stride + r0 + r] (f16). smem >= 64*65*4 bytes.
template <int NT>
__device__ __forceinline__ void cvt_tile64(const float* __restrict__ in,
                                           half_t* __restrict__ out,
                                           int r0, int c0, int out_stride,
                                           char* smem) {
    float (*tile)[65] = (float(*)[65])smem;
    int tid = threadIdx.x;
#pragma unroll
    for (int it = 0; it < 1024 / NT; it++) {
        int idx = tid + it * NT;
        int r = idx >> 4, c4 = (idx & 15) * 4;
        float4 v = *(const float4*)(in + (size_t)(r0 + r) * 1024 + c0 + c4);
        tile[r][c4] = v.x; tile[r][c4 + 1] = v.y; tile[r][c4 + 2] = v.z; tile[r][c4 + 3] = v.w;
    }
    __syncthreads();
#pragma unroll
    for (int it = 0; it < 1024 / NT; it++) {
        int idx = tid + it * NT;
        int oc = idx >> 4, r4 = (idx & 15) * 4;
        f16x4 o;
        o[0] = (half_t)tile[r4][oc];
        o[1] = (half_t)tile[r4 + 1][oc];
        o[2] = (half_t)tile[r4 + 2][oc];
        o[3] = (half_t)tile[r4 + 3][oc];
        *(f16x4*)(out + (size_t)(c0 + oc) * out_stride + r0 + r4) = o;
    }
}

// ---- fused prep: cvt x->f16 | route | cvt gate_up weights ----
// grid: [0,1024) cvt_x, [1024] route, [1025,3073) cvt_wgu
__global__ __launch_bounds__(256) void k_prep(const float* __restrict__ x,
                                              const int* __restrict__ ridx,
                                              const float* __restrict__ rw,
                                              const float* __restrict__ wgu,
                                              half_t* __restrict__ xb,
                                              half_t* __restrict__ wguT,
                                              int* __restrict__ meta,
                                              float* __restrict__ pair_w) {
    __shared__ char smem[16704];
    int b = blockIdx.x, tid = threadIdx.x;
    if (b < 1024) {
        int g = b * 256 + tid;
        size_t b0 = (size_t)g * 8;
        float4 v0 = *(const float4*)(x + b0);
        float4 v1 = *(const float4*)(x + b0 + 4);
        f16x8 o;
        o[0] = (half_t)v0.x; o[1] = (half_t)v0.y; o[2] = (half_t)v0.z; o[3] = (half_t)v0.w;
        o[4] = (half_t)v1.x; o[5] = (half_t)v1.y; o[6] = (half_t)v1.z; o[7] = (half_t)v1.w;
        *(f16x8*)(xb + b0) = o;
    } else if (b == 1024) {
        __shared__ int cnt[E_NUM], cur[E_NUM], base[E_NUM];
        if (tid < E_NUM) { cnt[tid] = 0; cur[tid] = 0; }
        __syncthreads();
        for (int i = tid; i < NPAIR; i += 256) atomicAdd(&cnt[ridx[i]], 1);
        __syncthreads();
        if (tid == 0) {
            int acc = 0, nt = 0;
            for (int e = 0; e < E_NUM; e++) {
                base[e] = acc;
                for (int r = 0; r < cnt[e]; r += BM) {
                    meta[8 + nt] = e; meta[88 + nt] = acc + r; meta[168 + nt] = acc + cnt[e]; nt++;
                }
                acc += cnt[e];
            }
            meta[0] = nt;
        }
        __syncthreads();
        for (int i = tid; i < NPAIR; i += 256) {
            int e = ridx[i];
            int pos = atomicAdd(&cur[e], 1);
            int slot = base[e] + pos;
            meta[256 + slot] = i >> 1;            // pair_token[slot] = t
            meta[256 + NPAIR + i] = slot;         // slot_of[pair i]
            pair_w[slot] = rw[i];
        }
    } else {
        int t = b - 1025;                 // [0, 2048): gate_up expert tiles
        int e = t >> 8, rem = t & 255;
        int h0 = (rem >> 4) * 64, f0 = (rem & 15) * 64;
        cvt_tile64<256>(wgu + (size_t)e * 1024 * 1024, wguT + (size_t)e * 1024 * 1024,
                        h0, f0, 1024, smem);
    }
}

// MODE 0: A = xb gathered rows (K=1024), B = wguT; epilogue = in-register SwiGLU -> inter f16.
//         extra blocks: [576,1600) cvt down-proj weights.
// MODE 1: A = inter (K=512), B = wdnT; epilogue = plain f16 stores of acc*pair_w to
//         contrib[slot][1024] -- no atomics (R14: agent-scope atomics cost ~40us).
// GEMM blocks: 1D XCD swizzle -> one expert's tiles stay on one XCD (L2-resident weights).
// Double-buffered LDS (proven R6/R8/R15 structure): stage(kt+1) issued before compute(kt);
// one __syncthreads per K-step.
template <int MODE>
__global__ __launch_bounds__(256) void k_gemm(const int* __restrict__ meta,
                                              const half_t* __restrict__ amat,
                                              const half_t* __restrict__ wT,
                                              const float* __restrict__ pair_w,
                                              void* __restrict__ outp,
                                              const float* __restrict__ aux_in,
                                              half_t* __restrict__ aux_out) {
    constexpr int KSZ = MODE ? ID : H_DIM;
    constexpr int NKT = KSZ / 64;
    __shared__ __align__(16) char smem[49152];   // [0,16K): As 2 bufs; [16K,48K): Bs 2 bufs

    int d = blockIdx.x;
    if (MODE == 0 && d >= 576) {
        int d2 = d - 576;          // cvt down-proj: in [e][512 i][1024 h] -> out [e][h][i]
        int e = d2 >> 7, rem = d2 & 127;
        int h0 = (rem >> 3) * 64, i0 = (rem & 7) * 64;
        cvt_tile64<256>(aux_in + (size_t)e * ID * 1024, aux_out + (size_t)e * 1024 * ID,
                        i0, h0, ID, smem);
        return;
    }

    int l = (d & 7) * MAXTILES + (d >> 3);    // XCD c owns l in [c*72, c*72+72)
    int bx = l >> 3, by = l & 7;
    int nt = meta[0];
    if (bx >= nt) return;
    int e = meta[8 + bx], row0 = meta[88 + bx], rend = meta[168 + bx];
    const int* pair_token = meta + 256;

    int tid = threadIdx.x, lane = tid & 63, wid = tid >> 6;

    // staging sources (16B chunks; XOR swizzle on the global source, linear LDS dest)
    const half_t* asrc[2]; int aoff[2];
#pragma unroll
    for (int i = 0; i < 2; i++) {
        int gch = wid * 2 + i, c = gch * 64 + lane;
        int r = c >> 3, pc = c & 7, lc = pc ^ (r & 7);
        int pr = row0 + r; if (pr > NPAIR - 1) pr = NPAIR - 1;
        const half_t* rowp = (MODE == 0) ? amat + (size_t)pair_token[pr] * KSZ
                                         : amat + (size_t)pr * KSZ;
        asrc[i] = rowp + lc * 8;
        aoff[i] = gch * 1024 + lane * 16;
    }
    const half_t* wbase = wT + (size_t)e * 1024 * KSZ;
    const half_t* bsrc[4]; int boff[4];
#pragma unroll
    for (int i = 0; i < 4; i++) {
        int gch = wid * 4 + i, c = gch * 64 + lane;
        int r = c >> 3, pc = c & 7, lc = pc ^ (r & 7);
        int physcol;
        if (MODE == 0) {
            int wn_r = r >> 5, fn_r = (r >> 4) & 1, ll = r & 15;
            physcol = by * 64 + wn_r * 16 + ll + (fn_r ? 512 : 0);
        } else {
            physcol = by * 128 + r;
        }
        bsrc[i] = wbase + (size_t)physcol * KSZ + lc * 8;
        boff[i] = gch * 1024 + lane * 16;
    }

#define STAGE(buf, kt)                                                             \
    {                                                                              \
        _Pragma("unroll")                                                          \
        for (int i = 0; i < 2; i++)                                                \
            gload_lds16(asrc[i] + (kt) * 64, smem + (buf) * 8192 + aoff[i]);       \
        _Pragma("unroll")                                                          \
        for (int i = 0; i < 4; i++)                                                \
            gload_lds16(bsrc[i] + (kt) * 64, smem + 16384 + (buf) * 16384 + boff[i]); \
    }

    f32x4 acc[4][2] = {};

    STAGE(0, 0);
    __syncthreads();   // buf0 ready

    for (int kt = 0; kt < NKT; kt++) {
        int cur = kt & 1;
        if (kt + 1 < NKT) STAGE(cur ^ 1, kt + 1);   // issue next tile early
        const char* Ab = smem + cur * 8192;
        const char* Bb = smem + 16384 + cur * 16384;
#pragma unroll
        for (int ks = 0; ks < 2; ks++) {
            f16x8 af[4], bf2[2];
#pragma unroll
            for (int f = 0; f < 4; f++) {
                int ar = f * 16 + (lane & 15);
                int apc = (ks * 4 + (lane >> 4)) ^ (ar & 7);
                af[f] = *(const f16x8*)(Ab + ar * 128 + apc * 16);
            }
#pragma unroll
            for (int f = 0; f < 2; f++) {
                int br = wid * 32 + f * 16 + (lane & 15);
                int bpc = (ks * 4 + (lane >> 4)) ^ (br & 7);
                bf2[f] = *(const f16x8*)(Bb + br * 128 + bpc * 16);
            }
#pragma unroll
            for (int fm = 0; fm < 4; fm++)
#pragma unroll
                for (int fn = 0; fn < 2; fn++)
                    acc[fm][fn] = __builtin_amdgcn_mfma_f32_16x16x32_f16(af[fm], bf2[fn], acc[fm][fn], 0, 0, 0);
        }
        __syncthreads();   // drains vmcnt: next buf ready; all reads of cur done
    }

    // C/D layout: col = lane&15, row = (lane>>4)*4 + j
    if (MODE == 0) {
        half_t* inter = (half_t*)outp;
#pragma unroll
        for (int fm = 0; fm < 4; fm++) {
            int rbase = fm * 16 + (lane >> 4) * 4;
#pragma unroll
            for (int j = 0; j < 4; j++) {
                int packed = row0 + rbase + j;
                if (packed < rend) {
                    float gv = acc[fm][0][j], uv = acc[fm][1][j];
                    float s = gv / (1.0f + __expf(-gv)) * uv;
                    int col = by * 64 + wid * 16 + (lane & 15);
                    inter[(size_t)packed * ID + col] = (half_t)s;
                }
            }
        }
    } else {
        half_t* contrib = (half_t*)outp;
#pragma unroll
        for (int fm = 0; fm < 4; fm++) {
            int rbase = fm * 16 + (lane >> 4) * 4;
#pragma unroll
            for (int j = 0; j < 4; j++) {
                int packed = row0 + rbase + j;
                if (packed < rend) {
                    float pw = pair_w[packed];
#pragma unroll
                    for (int fn = 0; fn < 2; fn++) {
                        int col = by * 128 + wid * 32 + fn * 16 + (lane & 15);
                        contrib[(size_t)packed * H_DIM + col] = (half_t)(acc[fm][fn][j] * pw);
                    }
                }
            }
        }
    }
#undef STAGE
}

// out[t] = contrib[slot_of[2t]] + contrib[slot_of[2t+1]]  (f16 rows, f32 sum; no atomics)
__global__ __launch_bounds__(256) void k_gather(const half_t* __restrict__ contrib,
                                                const int* __restrict__ meta,
                                                float* __restrict__ out) {
    int t = blockIdx.x, c4 = threadIdx.x * 4;
    const int* slot_of = meta + 256 + NPAIR;
    int s0 = slot_of[2 * t], s1 = slot_of[2 * t + 1];
    f16x4 a = *(const f16x4*)(contrib + (size_t)s0 * H_DIM + c4);
    f16x4 b = *(const f16x4*)(contrib + (size_t)s1 * H_DIM + c4);
    float4 o;
    o.x = (float)a[0] + (float)b[0];
    o.y = (float)a[1] + (float)b[1];
    o.z = (float)a[2] + (float)b[2];
    o.w = (float)a[3] + (float)b[3];
    *(float4*)(out + (size_t)t * H_DIM + c4) = o;
}

extern "C" void kernel_launch(void* const* d_in, const int* in_sizes, int n_in,
                              void* d_out, int out_size, void* d_ws, size_t ws_size,
                              hipStream_t stream) {
    const float* x    = (const float*)d_in[0];
    const int*   ridx = (const int*)d_in[1];
    const float* rw   = (const float*)d_in[2];
    const float* wgu  = (const float*)d_in[3];
    const float* wdn  = (const float*)d_in[4];
    float* out = (float*)d_out;

    char* ws = (char*)d_ws;
    half_t* xb      = (half_t*)(ws + XB_OFF);
    half_t* wguT    = (half_t*)(ws + WGU_OFF);
    half_t* wdnT    = (half_t*)(ws + WDN_OFF);
    half_t* inter   = (half_t*)(ws + INTER_OFF);
    int*    meta    = (int*)(ws + META_OFF);
    float*  pair_w  = (float*)(ws + PAIRW_OFF);
    half_t* contrib = (half_t*)(ws + CONTRIB_OFF);

    // L1: cvt_x (1024) | route (1) | cvt gate_up (2048)
    k_prep<<<3073, 256, 0, stream>>>(x, ridx, rw, wgu, xb, wguT, meta, pair_w);
    // L2: GEMM1 (576) | cvt down (1024)
    k_gemm<0><<<1600, 256, 0, stream>>>(meta, xb, wguT, pair_w, inter, wdn, wdnT);
    // L3: GEMM2 (576) -> contrib f16, plain stores
    k_gemm<1><<<576, 256, 0, stream>>>(meta, inter, wdnT, pair_w, contrib, nullptr, nullptr);
    // L4: gather (2048)
    k_gather<<<T_TOK, 256, 0, stream>>>(contrib, meta, out);
}